// Round 17
// baseline (368.319 us; speedup 1.0000x reference)
//
#include <hip/hip_runtime.h>
#include <hip/hip_bf16.h>
#include <cstdint>

// MoE SwiGLU: E=8 experts, top-2, D=1024, H=2048, T=4096 tokens.
// Round 17: round-16 + XCD-locality remap inside gemm1 ONLY:
// ct'=(x%8)*4+(y%4), rt'=(x>>3)*8+(y>>2)  =>  XCD (=x%8) owns a fixed 4-ct
// B-band (L2-resident, reused 8x/expert); live blocks stay balanced across
// XCDs for any cN (live rt' sweeps x=0..7 first — round-4 bug impossible).

#define E_ 8
#define D_ 1024
#define H_ 2048
#define T_ 4096

typedef __attribute__((ext_vector_type(8))) __bf16 bf16x8;
typedef __attribute__((ext_vector_type(4))) float f32x4;
typedef unsigned short u16;
typedef __attribute__((ext_vector_type(4))) u16 u16x4;

__device__ __forceinline__ u16 f2b(float f) {
    union { float f; unsigned int u; } v; v.f = f;
    unsigned int u = v.u;
    return (u16)((u + 0x7FFFu + ((u >> 16) & 1u)) >> 16);  // RNE
}

__device__ __forceinline__ float b2f(u16 v) {
    union { unsigned int u; float f; } x; x.u = (unsigned int)v << 16; return x.f;
}

__device__ __forceinline__ void gld16(const void* g, void* l) {
    __builtin_amdgcn_global_load_lds((const __attribute__((address_space(1))) void*)g,
                                     (__attribute__((address_space(3))) void*)l, 16, 0, 0);
}

// ---- k_prep: merged {weight transpose+cvt} and {gate}. grid (32,16,26). ----
__global__ void k_prep(const float* __restrict__ W0, const float* __restrict__ W1,
                       const float* __restrict__ W2, u16* __restrict__ w0t,
                       u16* __restrict__ w1t, u16* __restrict__ w2t,
                       const float* __restrict__ x, const float* __restrict__ gw,
                       int* __restrict__ cnt2, int4* __restrict__ tslot,
                       float2* __restrict__ twgt, u16* __restrict__ xb) {
    __shared__ __align__(16) char smem[32768];
    int z = blockIdx.z;
    int tid = threadIdx.x;
    if (z < 24) {
        float (*tile)[67] = (float(*)[67])smem;  // 64x67 = 17KB
        int which = z >> 3, e = z & 7;
        const float* src; u16* dst; int R, C, c0, r0;
        if (which == 0)      { src = W0 + (size_t)e * D_ * H_; dst = w0t + (size_t)e * D_ * H_;
                               R = D_; C = H_; c0 = blockIdx.x * 64; r0 = blockIdx.y * 64; }
        else if (which == 1) { src = W1 + (size_t)e * D_ * H_; dst = w1t + (size_t)e * D_ * H_;
                               R = D_; C = H_; c0 = blockIdx.x * 64; r0 = blockIdx.y * 64; }
        else                 { src = W2 + (size_t)e * H_ * D_; dst = w2t + (size_t)e * H_ * D_;
                               R = H_; C = D_; c0 = blockIdx.y * 64; r0 = blockIdx.x * 64; }
        int tc4 = (tid & 15) * 4, tr = tid >> 4;
#pragma unroll
        for (int p = 0; p < 4; ++p) {
            float4 v = *(const float4*)(src + (size_t)(r0 + tr + 16 * p) * C + c0 + tc4);
            tile[tr + 16 * p][tc4 + 0] = v.x;
            tile[tr + 16 * p][tc4 + 1] = v.y;
            tile[tr + 16 * p][tc4 + 2] = v.z;
            tile[tr + 16 * p][tc4 + 3] = v.w;
        }
        __syncthreads();
        int r4 = (tid & 15) * 4, tc = tid >> 4;
#pragma unroll
        for (int p = 0; p < 4; ++p) {
            int c = tc + 16 * p;
            u16x4 o;
#pragma unroll
            for (int j = 0; j < 4; ++j) o[j] = f2b(tile[r4 + j][c]);
            *(u16x4*)(dst + (size_t)(c0 + c) * R + r0 + r4) = o;
        }
    } else {
        float* gws = (float*)smem;  // 8192 floats = 32KB
        int gb = (z - 24) * 512 + blockIdx.y * 32 + blockIdx.x;  // 0..1023
#pragma unroll
        for (int p = 0; p < 8; ++p) {
            int i = (p * 256 + tid) * 4;
            *(float4*)&gws[i] = *(const float4*)&gw[i];
        }
        __syncthreads();
        int wid = tid >> 6, lane = tid & 63;
        int t = gb * 4 + wid;
        int chunk = gb & 63;
        const float* xr = x + (size_t)t * D_;
        float part[E_];
#pragma unroll
        for (int e = 0; e < E_; ++e) part[e] = 0.f;
#pragma unroll
        for (int i = 0; i < 4; ++i) {
            int d = i * 256 + lane * 4;
            float4 xv = *(const float4*)(xr + d);
            u16x4 o;
            o[0] = f2b(xv.x); o[1] = f2b(xv.y); o[2] = f2b(xv.z); o[3] = f2b(xv.w);
            *(u16x4*)(xb + (size_t)t * D_ + d) = o;
#pragma unroll
            for (int e = 0; e < E_; ++e) {
                float4 g = *(const float4*)&gws[e * D_ + d];
                part[e] += xv.x * g.x + xv.y * g.y + xv.z * g.z + xv.w * g.w;
            }
        }
#pragma unroll
        for (int off = 32; off >= 1; off >>= 1) {
#pragma unroll
            for (int e = 0; e < E_; ++e) part[e] += __shfl_xor(part[e], off);
        }
        if (lane == 0) {
            int e0 = 0; float m0 = part[0];
#pragma unroll
            for (int e = 1; e < E_; ++e) if (part[e] > m0) { m0 = part[e]; e0 = e; }
            int e1 = -1; float m1 = -3.4e38f;
#pragma unroll
            for (int e = 0; e < E_; ++e) if (e != e0 && part[e] > m1) { m1 = part[e]; e1 = e; }
            float sx = __expf(m1 - m0);
            float w0 = 1.f / (1.f + sx);
            float w1 = sx / (1.f + sx);
            int lp0 = atomicAdd(&cnt2[chunk * 16 + e0], 1);  // 1 cache line per chunk
            int lp1 = atomicAdd(&cnt2[chunk * 16 + e1], 1);
            tslot[t] = make_int4(e0, lp0, e1, lp1);
            twgt[t] = make_float2(w0, w1);
        }
    }
}

// ---- scan2: per-expert chunk prefix (exclusive), offs, cnt ----
__global__ void k_scan2(const int* __restrict__ cnt2, int* __restrict__ chunk_off,
                        int* __restrict__ cnt, int* __restrict__ offs) {
    __shared__ int totals[E_];
    int e = threadIdx.x >> 6, lane = threadIdx.x & 63;   // wave = expert
    int v = cnt2[lane * 16 + e];
    int incl = v;
#pragma unroll
    for (int d = 1; d < 64; d <<= 1) {
        int u = __shfl_up(incl, d);
        if (lane >= d) incl += u;
    }
    int excl = incl - v;
    if (lane == 63) totals[e] = incl;
    __syncthreads();
    chunk_off[lane * 8 + e] = excl;        // per-expert position base
    if (lane == 0) {
        int off_e = 0;
        for (int q = 0; q < e; ++q) off_e += totals[q];
        offs[e] = off_e; cnt[e] = totals[e];
    }
}

// ---- fixup: local slot -> per-expert slot; build tok lists ----
__global__ void k_fixup(const int* __restrict__ chunk_off, int4* __restrict__ tslot,
                        int* __restrict__ tok) {
    int t = blockIdx.x * 256 + threadIdx.x;
    int chunk = (t >> 2) & 63;
    int4 r = tslot[t];
    int s0 = chunk_off[chunk * 8 + r.x] + r.y;   // per-expert slot, < cnt[e]
    int s1 = chunk_off[chunk * 8 + r.z] + r.w;
    tok[r.x * T_ + s0] = t;
    tok[r.z * T_ + s1] = t;
    tslot[t] = make_int4(r.x, s0, r.z, s1);
}

// ---- GEMM1: gathered X[128,1024] @ {W0t,W1t}[64-col tile] -> g, bf16.
//      XCD-locality remap: XCD(x%8) owns a fixed 4-ct band. ----
__launch_bounds__(256, 2)
__global__ void k_gemm1(const u16* __restrict__ xb, const u16* __restrict__ w0t,
                        const u16* __restrict__ w1t, const float* __restrict__ b0,
                        const float* __restrict__ b1, const int* __restrict__ tok,
                        const int* __restrict__ cnt, const int* __restrict__ offs,
                        u16* __restrict__ gbuf) {
    int e = blockIdx.z;
    int bx = blockIdx.x, by = blockIdx.y;
    int ct = (bx & 7) * 4 + (by & 3);          // XCD = bx%8 -> fixed 4-ct band
    int rt = (bx >> 3) * 8 + (by >> 2);        // live rt sweeps bx 0..7 first
    int cN = cnt[e];
    if (rt * 128 >= cN) return;
    __shared__ u16 lds[16384];  // A:[128][64] @0, B0:[64][64] @16KB, B1 @24KB (bytes)
    char* ldsB = (char*)lds;
    int tid = threadIdx.x, wid = tid >> 6, lane = tid & 63;
    int wm = wid >> 1, wn = wid & 1;
    const int* tokE = tok + e * T_;
    const u16* w0e = w0t + (size_t)e * H_ * D_;
    const u16* w1e = w1t + (size_t)e * H_ * D_;

    size_t aoff[4]; int adst[4];
#pragma unroll
    for (int p = 0; p < 4; ++p) {
        int cid = p * 256 + tid, r = cid >> 3, c = cid & 7;
        int cc = c ^ (r & 7);                       // pre-swizzled source chunk
        int tk = tokE[min(rt * 128 + r, cN - 1)];   // gather (clamped padding)
        aoff[p] = (size_t)tk * D_ + cc * 8;
        adst[p] = (p * 256 + wid * 64) * 16;
    }
    size_t boff[2]; int bdst[2];
#pragma unroll
    for (int p = 0; p < 2; ++p) {
        int cid = p * 256 + tid, n = cid >> 3, c = cid & 7;
        int cc = c ^ (n & 7);
        boff[p] = (size_t)(ct * 64 + n) * D_ + cc * 8;
        bdst[p] = (p * 256 + wid * 64) * 16;
    }

    f32x4 acc0[4][2], acc1[4][2];
#pragma unroll
    for (int m = 0; m < 4; ++m)
#pragma unroll
        for (int n = 0; n < 2; ++n) { acc0[m][n] = (f32x4)0.f; acc1[m][n] = (f32x4)0.f; }

    for (int kt = 0; kt < D_ / 64; ++kt) {
        int k0 = kt * 64;
        __syncthreads();
#pragma unroll
        for (int p = 0; p < 4; ++p) gld16(xb + aoff[p] + k0, ldsB + adst[p]);
#pragma unroll
        for (int p = 0; p < 2; ++p) gld16(w0e + boff[p] + k0, ldsB + 16384 + bdst[p]);
#pragma unroll
        for (int p = 0; p < 2; ++p) gld16(w1e + boff[p] + k0, ldsB + 24576 + bdst[p]);
        __syncthreads();
#pragma unroll
        for (int ks = 0; ks < 2; ++ks) {
            int kc = ks * 4 + (lane >> 4);
            bf16x8 af[4], b0f[2], b1f[2];
#pragma unroll
            for (int m = 0; m < 4; ++m) {
                int row = wm * 64 + m * 16 + (lane & 15);
                af[m] = *(const bf16x8*)(ldsB + row * 128 + ((kc ^ (row & 7)) << 4));
            }
#pragma unroll
            for (int n = 0; n < 2; ++n) {
                int nr = wn * 32 + n * 16 + (lane & 15);
                int so = (kc ^ (nr & 7)) << 4;
                b0f[n] = *(const bf16x8*)(ldsB + 16384 + nr * 128 + so);
                b1f[n] = *(const bf16x8*)(ldsB + 24576 + nr * 128 + so);
            }
#pragma unroll
            for (int m = 0; m < 4; ++m)
#pragma unroll
                for (int n = 0; n < 2; ++n) {
                    acc0[m][n] = __builtin_amdgcn_mfma_f32_16x16x32_bf16(af[m], b0f[n], acc0[m][n], 0, 0, 0);
                    acc1[m][n] = __builtin_amdgcn_mfma_f32_16x16x32_bf16(af[m], b1f[n], acc1[m][n], 0, 0, 0);
                }
        }
    }
    int off_e = offs[e];
    const float* b0e = b0 + e * H_;
    const float* b1e = b1 + e * H_;
#pragma unroll
    for (int n = 0; n < 2; ++n) {
        int hc = ct * 64 + wn * 32 + n * 16 + (lane & 15);
        float bb0 = b0e[hc], bb1 = b1e[hc];
#pragma unroll
        for (int m = 0; m < 4; ++m)
#pragma unroll
            for (int i = 0; i < 4; ++i) {
                int row = wm * 64 + m * 16 + (lane >> 4) * 4 + i;
                int idx = rt * 128 + row;
                if (idx < cN) {
                    float h0 = acc0[m][n][i] + bb0;
                    float h1 = acc1[m][n][i] + bb1;
                    float g = h0 * h1 / (1.f + __expf(-h1));
                    gbuf[(size_t)(off_e + idx) * H_ + hc] = f2b(g);
                }
            }
    }
}

// ---- GEMM2 (round-12): g[128,2048] @ W2t[128-col tile] -> y bf16 (incl b2) ----
__launch_bounds__(256, 2)
__global__ void k_gemm2(const u16* __restrict__ gbuf, const u16* __restrict__ w2t,
                        const float* __restrict__ b2, const int* __restrict__ cnt,
                        const int* __restrict__ offs, u16* __restrict__ yb) {
    int e = blockIdx.z, rt = blockIdx.y, ct = blockIdx.x;
    int cN = cnt[e];
    if (rt * 128 >= cN) return;
    __shared__ u16 lds[16384];  // A:[128][64] @0, B:[128][64] @16KB (bytes)
    char* ldsB = (char*)lds;
    int tid = threadIdx.x, wid = tid >> 6, lane = tid & 63;
    int wm = wid >> 1, wn = wid & 1;
    int off_e = offs[e];
    const u16* Ag = gbuf + (size_t)(off_e + rt * 128) * H_;  // padded tail allows over-read
    const u16* Bw = w2t + (size_t)e * D_ * H_ + (size_t)(ct * 128) * H_;

    size_t soff[4]; int sdst[4];
#pragma unroll
    for (int p = 0; p < 4; ++p) {
        int cid = p * 256 + tid, r = cid >> 3, c = cid & 7;
        int cc = c ^ (r & 7);
        soff[p] = (size_t)r * H_ + cc * 8;
        sdst[p] = (p * 256 + wid * 64) * 16;
    }
    f32x4 acc[4][4];
#pragma unroll
    for (int m = 0; m < 4; ++m)
#pragma unroll
        for (int n = 0; n < 4; ++n) acc[m][n] = (f32x4)0.f;

    for (int kt = 0; kt < H_ / 64; ++kt) {
        int k0 = kt * 64;
        __syncthreads();
#pragma unroll
        for (int p = 0; p < 4; ++p) gld16(Ag + soff[p] + k0, ldsB + sdst[p]);
#pragma unroll
        for (int p = 0; p < 4; ++p) gld16(Bw + soff[p] + k0, ldsB + 16384 + sdst[p]);
        __syncthreads();
#pragma unroll
        for (int ks = 0; ks < 2; ++ks) {
            int kc = ks * 4 + (lane >> 4);
            bf16x8 af[4], bfr[4];
#pragma unroll
            for (int m = 0; m < 4; ++m) {
                int row = wm * 64 + m * 16 + (lane & 15);
                af[m] = *(const bf16x8*)(ldsB + row * 128 + ((kc ^ (row & 7)) << 4));
            }
#pragma unroll
            for (int n = 0; n < 4; ++n) {
                int nr = wn * 64 + n * 16 + (lane & 15);
                bfr[n] = *(const bf16x8*)(ldsB + 16384 + nr * 128 + ((kc ^ (nr & 7)) << 4));
            }
#pragma unroll
            for (int m = 0; m < 4; ++m)
#pragma unroll
                for (int n = 0; n < 4; ++n)
                    acc[m][n] = __builtin_amdgcn_mfma_f32_16x16x32_bf16(af[m], bfr[n], acc[m][n], 0, 0, 0);
        }
    }
    const float* b2e = b2 + e * D_;
#pragma unroll
    for (int m = 0; m < 4; ++m)
#pragma unroll
        for (int i = 0; i < 4; ++i) {
            int row = wm * 64 + m * 16 + (lane >> 4) * 4 + i;
            int idx = rt * 128 + row;
            if (idx < cN) {
#pragma unroll
                for (int n = 0; n < 4; ++n) {
                    int dc = ct * 128 + wn * 64 + n * 16 + (lane & 15);
                    yb[(size_t)(off_e + idx) * D_ + dc] = f2b(acc[m][n][i] + b2e[dc]);
                }
            }
        }
}

// ---- combine: out[t] = w0*y[offs[e0]+slot0] + w1*y[offs[e1]+slot1] ----
__global__ void k_combine(const u16* __restrict__ yb, const int4* __restrict__ tslot,
                          const float2* __restrict__ twgt, const int* __restrict__ offs,
                          float* __restrict__ out) {
    int t = blockIdx.x, d4 = threadIdx.x * 4;
    int4 s = tslot[t];
    float2 w = twgt[t];
    const u16* y0 = yb + (size_t)(offs[s.x] + s.y) * D_ + d4;
    const u16* y1 = yb + (size_t)(offs[s.z] + s.w) * D_ + d4;
    u16x4 a = *(const u16x4*)y0;
    u16x4 b = *(const u16x4*)y1;
    float4 o;
    o.x = w.x * b2f(a[0]) + w.y * b2f(b[0]);
    o.y = w.x * b2f(a[1]) + w.y * b2f(b[1]);
    o.z = w.x * b2f(a[2]) + w.y * b2f(b[2]);
    o.w = w.x * b2f(a[3]) + w.y * b2f(b[3]);
    *(float4*)(out + (size_t)t * D_ + d4) = o;
}

extern "C" void kernel_launch(void* const* d_in, const int* in_sizes, int n_in,
                              void* d_out, int out_size, void* d_ws, size_t ws_size,
                              hipStream_t stream) {
    const float* x  = (const float*)d_in[0];
    const float* gw = (const float*)d_in[1];
    const float* W0 = (const float*)d_in[2];
    const float* b0 = (const float*)d_in[3];
    const float* W1 = (const float*)d_in[4];
    const float* b1 = (const float*)d_in[5];
    const float* W2 = (const float*)d_in[6];
    const float* b2 = (const float*)d_in[7];
    float* out = (float*)d_out;

    char* ws = (char*)d_ws;
    size_t off = 0;
    u16* xb   = (u16*)(ws + off); off += (size_t)T_ * D_ * 2;             // 8 MB
    u16* w0t  = (u16*)(ws + off); off += (size_t)E_ * H_ * D_ * 2;        // 32 MB
    u16* w1t  = (u16*)(ws + off); off += (size_t)E_ * H_ * D_ * 2;        // 32 MB
    u16* w2t  = (u16*)(ws + off); off += (size_t)E_ * D_ * H_ * 2;        // 32 MB
    u16* gbuf = (u16*)(ws + off); off += (size_t)(T_ * 2 + 256) * H_ * 2; // padded tail
    int*   tok   = (int*)(ws + off);    off += (size_t)E_ * T_ * 4;
    int4*  tslot = (int4*)(ws + off);   off += (size_t)T_ * 16;
    float2* twgt = (float2*)(ws + off); off += (size_t)T_ * 8;
    int*   cnt2  = (int*)(ws + off);    off += 64 * 16 * 4;   // 64 chunks x 1 line
    int*   choff = (int*)(ws + off);    off += 64 * 8 * 4;
    int*   cnt   = (int*)(ws + off);    off += 64;
    int*   offs  = (int*)(ws + off);    off += 64;
    // y reuses w0t's region (dead after gemm1; gemm2 runs strictly after gemm1)
    u16* yb = w0t;  // needs (2T+256)*D*2 = 17 MB <= 32 MB

    if (ws_size < off) return;  // workspace too small: leave output poisoned (visible failure)
    hipMemsetAsync(cnt2, 0, 64 * 16 * 4, stream);

    k_prep<<<dim3(32, 16, 26), 256, 0, stream>>>(W0, W1, W2, w0t, w1t, w2t,
                                                 x, gw, cnt2, tslot, twgt, xb);
    k_scan2<<<1, 512, 0, stream>>>(cnt2, choff, cnt, offs);
    k_fixup<<<T_ / 256, 256, 0, stream>>>(choff, tslot, tok);
    k_gemm1<<<dim3(H_ / 64, T_ / 128, E_), 256, 0, stream>>>(xb, w0t, w1t, b0, b1, tok, cnt, offs, gbuf);
    k_gemm2<<<dim3(D_ / 128, T_ / 128, E_), 256, 0, stream>>>(gbuf, w2t, b2, cnt, offs, yb);
    k_combine<<<T_, 256, 0, stream>>>(yb, tslot, twgt, offs, out);
}

// Round 18
// 232.390 us; speedup vs baseline: 1.5849x; 1.5849x over previous
//
#include <hip/hip_runtime.h>
#include <hip/hip_bf16.h>
#include <cstdint>

// MoE SwiGLU: E=8 experts, top-2, D=1024, H=2048, T=4096 tokens.
// Round 18: restore round-16 best (232us). gemm1/gemm2 = proven 2-barrier
// 128-tile structure, DEFAULT block mapping (both XCD remaps regressed:
// strided live blocks + early-exit = occupancy collapse). k_combine regrouped
// to 4 tokens/block. No schedule changes — 8 attempts all regressed.

#define E_ 8
#define D_ 1024
#define H_ 2048
#define T_ 4096

typedef __attribute__((ext_vector_type(8))) __bf16 bf16x8;
typedef __attribute__((ext_vector_type(4))) float f32x4;
typedef unsigned short u16;
typedef __attribute__((ext_vector_type(4))) u16 u16x4;

__device__ __forceinline__ u16 f2b(float f) {
    union { float f; unsigned int u; } v; v.f = f;
    unsigned int u = v.u;
    return (u16)((u + 0x7FFFu + ((u >> 16) & 1u)) >> 16);  // RNE
}

__device__ __forceinline__ float b2f(u16 v) {
    union { unsigned int u; float f; } x; x.u = (unsigned int)v << 16; return x.f;
}

__device__ __forceinline__ void gld16(const void* g, void* l) {
    __builtin_amdgcn_global_load_lds((const __attribute__((address_space(1))) void*)g,
                                     (__attribute__((address_space(3))) void*)l, 16, 0, 0);
}

// ---- k_prep: merged {weight transpose+cvt} and {gate}. grid (32,16,26). ----
__global__ void k_prep(const float* __restrict__ W0, const float* __restrict__ W1,
                       const float* __restrict__ W2, u16* __restrict__ w0t,
                       u16* __restrict__ w1t, u16* __restrict__ w2t,
                       const float* __restrict__ x, const float* __restrict__ gw,
                       int* __restrict__ cnt2, int4* __restrict__ tslot,
                       float2* __restrict__ twgt, u16* __restrict__ xb) {
    __shared__ __align__(16) char smem[32768];
    int z = blockIdx.z;
    int tid = threadIdx.x;
    if (z < 24) {
        float (*tile)[67] = (float(*)[67])smem;  // 64x67 = 17KB
        int which = z >> 3, e = z & 7;
        const float* src; u16* dst; int R, C, c0, r0;
        if (which == 0)      { src = W0 + (size_t)e * D_ * H_; dst = w0t + (size_t)e * D_ * H_;
                               R = D_; C = H_; c0 = blockIdx.x * 64; r0 = blockIdx.y * 64; }
        else if (which == 1) { src = W1 + (size_t)e * D_ * H_; dst = w1t + (size_t)e * D_ * H_;
                               R = D_; C = H_; c0 = blockIdx.x * 64; r0 = blockIdx.y * 64; }
        else                 { src = W2 + (size_t)e * H_ * D_; dst = w2t + (size_t)e * H_ * D_;
                               R = H_; C = D_; c0 = blockIdx.y * 64; r0 = blockIdx.x * 64; }
        int tc4 = (tid & 15) * 4, tr = tid >> 4;
#pragma unroll
        for (int p = 0; p < 4; ++p) {
            float4 v = *(const float4*)(src + (size_t)(r0 + tr + 16 * p) * C + c0 + tc4);
            tile[tr + 16 * p][tc4 + 0] = v.x;
            tile[tr + 16 * p][tc4 + 1] = v.y;
            tile[tr + 16 * p][tc4 + 2] = v.z;
            tile[tr + 16 * p][tc4 + 3] = v.w;
        }
        __syncthreads();
        int r4 = (tid & 15) * 4, tc = tid >> 4;
#pragma unroll
        for (int p = 0; p < 4; ++p) {
            int c = tc + 16 * p;
            u16x4 o;
#pragma unroll
            for (int j = 0; j < 4; ++j) o[j] = f2b(tile[r4 + j][c]);
            *(u16x4*)(dst + (size_t)(c0 + c) * R + r0 + r4) = o;
        }
    } else {
        float* gws = (float*)smem;  // 8192 floats = 32KB
        int gb = (z - 24) * 512 + blockIdx.y * 32 + blockIdx.x;  // 0..1023
#pragma unroll
        for (int p = 0; p < 8; ++p) {
            int i = (p * 256 + tid) * 4;
            *(float4*)&gws[i] = *(const float4*)&gw[i];
        }
        __syncthreads();
        int wid = tid >> 6, lane = tid & 63;
        int t = gb * 4 + wid;
        int chunk = gb & 63;
        const float* xr = x + (size_t)t * D_;
        float part[E_];
#pragma unroll
        for (int e = 0; e < E_; ++e) part[e] = 0.f;
#pragma unroll
        for (int i = 0; i < 4; ++i) {
            int d = i * 256 + lane * 4;
            float4 xv = *(const float4*)(xr + d);
            u16x4 o;
            o[0] = f2b(xv.x); o[1] = f2b(xv.y); o[2] = f2b(xv.z); o[3] = f2b(xv.w);
            *(u16x4*)(xb + (size_t)t * D_ + d) = o;
#pragma unroll
            for (int e = 0; e < E_; ++e) {
                float4 g = *(const float4*)&gws[e * D_ + d];
                part[e] += xv.x * g.x + xv.y * g.y + xv.z * g.z + xv.w * g.w;
            }
        }
#pragma unroll
        for (int off = 32; off >= 1; off >>= 1) {
#pragma unroll
            for (int e = 0; e < E_; ++e) part[e] += __shfl_xor(part[e], off);
        }
        if (lane == 0) {
            int e0 = 0; float m0 = part[0];
#pragma unroll
            for (int e = 1; e < E_; ++e) if (part[e] > m0) { m0 = part[e]; e0 = e; }
            int e1 = -1; float m1 = -3.4e38f;
#pragma unroll
            for (int e = 0; e < E_; ++e) if (e != e0 && part[e] > m1) { m1 = part[e]; e1 = e; }
            float sx = __expf(m1 - m0);
            float w0 = 1.f / (1.f + sx);
            float w1 = sx / (1.f + sx);
            int lp0 = atomicAdd(&cnt2[chunk * 16 + e0], 1);  // 1 cache line per chunk
            int lp1 = atomicAdd(&cnt2[chunk * 16 + e1], 1);
            tslot[t] = make_int4(e0, lp0, e1, lp1);
            twgt[t] = make_float2(w0, w1);
        }
    }
}

// ---- scan2: per-expert chunk prefix (exclusive), offs, cnt ----
__global__ void k_scan2(const int* __restrict__ cnt2, int* __restrict__ chunk_off,
                        int* __restrict__ cnt, int* __restrict__ offs) {
    __shared__ int totals[E_];
    int e = threadIdx.x >> 6, lane = threadIdx.x & 63;   // wave = expert
    int v = cnt2[lane * 16 + e];
    int incl = v;
#pragma unroll
    for (int d = 1; d < 64; d <<= 1) {
        int u = __shfl_up(incl, d);
        if (lane >= d) incl += u;
    }
    int excl = incl - v;
    if (lane == 63) totals[e] = incl;
    __syncthreads();
    chunk_off[lane * 8 + e] = excl;        // per-expert position base
    if (lane == 0) {
        int off_e = 0;
        for (int q = 0; q < e; ++q) off_e += totals[q];
        offs[e] = off_e; cnt[e] = totals[e];
    }
}

// ---- fixup: local slot -> per-expert slot; build tok lists ----
__global__ void k_fixup(const int* __restrict__ chunk_off, int4* __restrict__ tslot,
                        int* __restrict__ tok) {
    int t = blockIdx.x * 256 + threadIdx.x;
    int chunk = (t >> 2) & 63;
    int4 r = tslot[t];
    int s0 = chunk_off[chunk * 8 + r.x] + r.y;   // per-expert slot, < cnt[e]
    int s1 = chunk_off[chunk * 8 + r.z] + r.w;
    tok[r.x * T_ + s0] = t;
    tok[r.z * T_ + s1] = t;
    tslot[t] = make_int4(r.x, s0, r.z, s1);
}

// ---- GEMM1 (round-12/16): gathered X[128,1024] @ {W0t,W1t}[64-col tile] ----
__launch_bounds__(256, 2)
__global__ void k_gemm1(const u16* __restrict__ xb, const u16* __restrict__ w0t,
                        const u16* __restrict__ w1t, const float* __restrict__ b0,
                        const float* __restrict__ b1, const int* __restrict__ tok,
                        const int* __restrict__ cnt, const int* __restrict__ offs,
                        u16* __restrict__ gbuf) {
    int e = blockIdx.z, rt = blockIdx.y, ct = blockIdx.x;  // default map: live rows lead
    int cN = cnt[e];
    if (rt * 128 >= cN) return;
    __shared__ u16 lds[16384];  // A:[128][64] @0, B0:[64][64] @16KB, B1 @24KB (bytes)
    char* ldsB = (char*)lds;
    int tid = threadIdx.x, wid = tid >> 6, lane = tid & 63;
    int wm = wid >> 1, wn = wid & 1;
    const int* tokE = tok + e * T_;
    const u16* w0e = w0t + (size_t)e * H_ * D_;
    const u16* w1e = w1t + (size_t)e * H_ * D_;

    size_t aoff[4]; int adst[4];
#pragma unroll
    for (int p = 0; p < 4; ++p) {
        int cid = p * 256 + tid, r = cid >> 3, c = cid & 7;
        int cc = c ^ (r & 7);                       // pre-swizzled source chunk
        int tk = tokE[min(rt * 128 + r, cN - 1)];   // gather (clamped padding)
        aoff[p] = (size_t)tk * D_ + cc * 8;
        adst[p] = (p * 256 + wid * 64) * 16;
    }
    size_t boff[2]; int bdst[2];
#pragma unroll
    for (int p = 0; p < 2; ++p) {
        int cid = p * 256 + tid, n = cid >> 3, c = cid & 7;
        int cc = c ^ (n & 7);
        boff[p] = (size_t)(ct * 64 + n) * D_ + cc * 8;
        bdst[p] = (p * 256 + wid * 64) * 16;
    }

    f32x4 acc0[4][2], acc1[4][2];
#pragma unroll
    for (int m = 0; m < 4; ++m)
#pragma unroll
        for (int n = 0; n < 2; ++n) { acc0[m][n] = (f32x4)0.f; acc1[m][n] = (f32x4)0.f; }

    for (int kt = 0; kt < D_ / 64; ++kt) {
        int k0 = kt * 64;
        __syncthreads();
#pragma unroll
        for (int p = 0; p < 4; ++p) gld16(xb + aoff[p] + k0, ldsB + adst[p]);
#pragma unroll
        for (int p = 0; p < 2; ++p) gld16(w0e + boff[p] + k0, ldsB + 16384 + bdst[p]);
#pragma unroll
        for (int p = 0; p < 2; ++p) gld16(w1e + boff[p] + k0, ldsB + 24576 + bdst[p]);
        __syncthreads();
#pragma unroll
        for (int ks = 0; ks < 2; ++ks) {
            int kc = ks * 4 + (lane >> 4);
            bf16x8 af[4], b0f[2], b1f[2];
#pragma unroll
            for (int m = 0; m < 4; ++m) {
                int row = wm * 64 + m * 16 + (lane & 15);
                af[m] = *(const bf16x8*)(ldsB + row * 128 + ((kc ^ (row & 7)) << 4));
            }
#pragma unroll
            for (int n = 0; n < 2; ++n) {
                int nr = wn * 32 + n * 16 + (lane & 15);
                int so = (kc ^ (nr & 7)) << 4;
                b0f[n] = *(const bf16x8*)(ldsB + 16384 + nr * 128 + so);
                b1f[n] = *(const bf16x8*)(ldsB + 24576 + nr * 128 + so);
            }
#pragma unroll
            for (int m = 0; m < 4; ++m)
#pragma unroll
                for (int n = 0; n < 2; ++n) {
                    acc0[m][n] = __builtin_amdgcn_mfma_f32_16x16x32_bf16(af[m], b0f[n], acc0[m][n], 0, 0, 0);
                    acc1[m][n] = __builtin_amdgcn_mfma_f32_16x16x32_bf16(af[m], b1f[n], acc1[m][n], 0, 0, 0);
                }
        }
    }
    int off_e = offs[e];
    const float* b0e = b0 + e * H_;
    const float* b1e = b1 + e * H_;
#pragma unroll
    for (int n = 0; n < 2; ++n) {
        int hc = ct * 64 + wn * 32 + n * 16 + (lane & 15);
        float bb0 = b0e[hc], bb1 = b1e[hc];
#pragma unroll
        for (int m = 0; m < 4; ++m)
#pragma unroll
            for (int i = 0; i < 4; ++i) {
                int row = wm * 64 + m * 16 + (lane >> 4) * 4 + i;
                int idx = rt * 128 + row;
                if (idx < cN) {
                    float h0 = acc0[m][n][i] + bb0;
                    float h1 = acc1[m][n][i] + bb1;
                    float g = h0 * h1 / (1.f + __expf(-h1));
                    gbuf[(size_t)(off_e + idx) * H_ + hc] = f2b(g);
                }
            }
    }
}

// ---- GEMM2 (round-12/16): g[128,2048] @ W2t[128-col tile] -> y bf16 (incl b2) ----
__launch_bounds__(256, 2)
__global__ void k_gemm2(const u16* __restrict__ gbuf, const u16* __restrict__ w2t,
                        const float* __restrict__ b2, const int* __restrict__ cnt,
                        const int* __restrict__ offs, u16* __restrict__ yb) {
    int e = blockIdx.z, rt = blockIdx.y, ct = blockIdx.x;
    int cN = cnt[e];
    if (rt * 128 >= cN) return;
    __shared__ u16 lds[16384];  // A:[128][64] @0, B:[128][64] @16KB (bytes)
    char* ldsB = (char*)lds;
    int tid = threadIdx.x, wid = tid >> 6, lane = tid & 63;
    int wm = wid >> 1, wn = wid & 1;
    int off_e = offs[e];
    const u16* Ag = gbuf + (size_t)(off_e + rt * 128) * H_;  // padded tail allows over-read
    const u16* Bw = w2t + (size_t)e * D_ * H_ + (size_t)(ct * 128) * H_;

    size_t soff[4]; int sdst[4];
#pragma unroll
    for (int p = 0; p < 4; ++p) {
        int cid = p * 256 + tid, r = cid >> 3, c = cid & 7;
        int cc = c ^ (r & 7);
        soff[p] = (size_t)r * H_ + cc * 8;
        sdst[p] = (p * 256 + wid * 64) * 16;
    }
    f32x4 acc[4][4];
#pragma unroll
    for (int m = 0; m < 4; ++m)
#pragma unroll
        for (int n = 0; n < 4; ++n) acc[m][n] = (f32x4)0.f;

    for (int kt = 0; kt < H_ / 64; ++kt) {
        int k0 = kt * 64;
        __syncthreads();
#pragma unroll
        for (int p = 0; p < 4; ++p) gld16(Ag + soff[p] + k0, ldsB + sdst[p]);
#pragma unroll
        for (int p = 0; p < 4; ++p) gld16(Bw + soff[p] + k0, ldsB + 16384 + sdst[p]);
        __syncthreads();
#pragma unroll
        for (int ks = 0; ks < 2; ++ks) {
            int kc = ks * 4 + (lane >> 4);
            bf16x8 af[4], bfr[4];
#pragma unroll
            for (int m = 0; m < 4; ++m) {
                int row = wm * 64 + m * 16 + (lane & 15);
                af[m] = *(const bf16x8*)(ldsB + row * 128 + ((kc ^ (row & 7)) << 4));
            }
#pragma unroll
            for (int n = 0; n < 4; ++n) {
                int nr = wn * 64 + n * 16 + (lane & 15);
                bfr[n] = *(const bf16x8*)(ldsB + 16384 + nr * 128 + ((kc ^ (nr & 7)) << 4));
            }
#pragma unroll
            for (int m = 0; m < 4; ++m)
#pragma unroll
                for (int n = 0; n < 4; ++n)
                    acc[m][n] = __builtin_amdgcn_mfma_f32_16x16x32_bf16(af[m], bfr[n], acc[m][n], 0, 0, 0);
        }
    }
    const float* b2e = b2 + e * D_;
#pragma unroll
    for (int m = 0; m < 4; ++m)
#pragma unroll
        for (int i = 0; i < 4; ++i) {
            int row = wm * 64 + m * 16 + (lane >> 4) * 4 + i;
            int idx = rt * 128 + row;
            if (idx < cN) {
#pragma unroll
                for (int n = 0; n < 4; ++n) {
                    int dc = ct * 128 + wn * 64 + n * 16 + (lane & 15);
                    yb[(size_t)(off_e + idx) * D_ + dc] = f2b(acc[m][n][i] + b2e[dc]);
                }
            }
        }
}

// ---- combine: 4 tokens/block (wave/token, 16 el/lane) ----
__global__ void k_combine(const u16* __restrict__ yb, const int4* __restrict__ tslot,
                          const float2* __restrict__ twgt, const int* __restrict__ offs,
                          float* __restrict__ out) {
    int wid = threadIdx.x >> 6, lane = threadIdx.x & 63;
    int t = blockIdx.x * 4 + wid;
    int4 s = tslot[t];
    float2 w = twgt[t];
    const u16* y0 = yb + (size_t)(offs[s.x] + s.y) * D_;
    const u16* y1 = yb + (size_t)(offs[s.z] + s.w) * D_;
    float* op = out + (size_t)t * D_;
#pragma unroll
    for (int p = 0; p < 4; ++p) {
        int d4 = p * 256 + lane * 4;
        u16x4 a = *(const u16x4*)(y0 + d4);
        u16x4 b = *(const u16x4*)(y1 + d4);
        float4 o;
        o.x = w.x * b2f(a[0]) + w.y * b2f(b[0]);
        o.y = w.x * b2f(a[1]) + w.y * b2f(b[1]);
        o.z = w.x * b2f(a[2]) + w.y * b2f(b[2]);
        o.w = w.x * b2f(a[3]) + w.y * b2f(b[3]);
        *(float4*)(op + d4) = o;
    }
}

extern "C" void kernel_launch(void* const* d_in, const int* in_sizes, int n_in,
                              void* d_out, int out_size, void* d_ws, size_t ws_size,
                              hipStream_t stream) {
    const float* x  = (const float*)d_in[0];
    const float* gw = (const float*)d_in[1];
    const float* W0 = (const float*)d_in[2];
    const float* b0 = (const float*)d_in[3];
    const float* W1 = (const float*)d_in[4];
    const float* b1 = (const float*)d_in[5];
    const float* W2 = (const float*)d_in[6];
    const float* b2 = (const float*)d_in[7];
    float* out = (float*)d_out;

    char* ws = (char*)d_ws;
    size_t off = 0;
    u16* xb   = (u16*)(ws + off); off += (size_t)T_ * D_ * 2;             // 8 MB
    u16* w0t  = (u16*)(ws + off); off += (size_t)E_ * H_ * D_ * 2;        // 32 MB
    u16* w1t  = (u16*)(ws + off); off += (size_t)E_ * H_ * D_ * 2;        // 32 MB
    u16* w2t  = (u16*)(ws + off); off += (size_t)E_ * D_ * H_ * 2;        // 32 MB
    u16* gbuf = (u16*)(ws + off); off += (size_t)(T_ * 2 + 256) * H_ * 2; // padded tail
    int*   tok   = (int*)(ws + off);    off += (size_t)E_ * T_ * 4;
    int4*  tslot = (int4*)(ws + off);   off += (size_t)T_ * 16;
    float2* twgt = (float2*)(ws + off); off += (size_t)T_ * 8;
    int*   cnt2  = (int*)(ws + off);    off += 64 * 16 * 4;   // 64 chunks x 1 line
    int*   choff = (int*)(ws + off);    off += 64 * 8 * 4;
    int*   cnt   = (int*)(ws + off);    off += 64;
    int*   offs  = (int*)(ws + off);    off += 64;
    // y reuses w0t's region (dead after gemm1; gemm2 runs strictly after gemm1)
    u16* yb = w0t;  // needs (2T+256)*D*2 = 17 MB <= 32 MB

    if (ws_size < off) return;  // workspace too small: leave output poisoned (visible failure)
    hipMemsetAsync(cnt2, 0, 64 * 16 * 4, stream);

    k_prep<<<dim3(32, 16, 26), 256, 0, stream>>>(W0, W1, W2, w0t, w1t, w2t,
                                                 x, gw, cnt2, tslot, twgt, xb);
    k_scan2<<<1, 512, 0, stream>>>(cnt2, choff, cnt, offs);
    k_fixup<<<T_ / 256, 256, 0, stream>>>(choff, tslot, tok);
    k_gemm1<<<dim3(H_ / 64, T_ / 128, E_), 256, 0, stream>>>(xb, w0t, w1t, b0, b1, tok, cnt, offs, gbuf);
    k_gemm2<<<dim3(D_ / 128, T_ / 128, E_), 256, 0, stream>>>(gbuf, w2t, b2, cnt, offs, yb);
    k_combine<<<T_ / 4, 256, 0, stream>>>(yb, tslot, twgt, offs, out);
}